// Round 4
// baseline (5665.051 us; speedup 1.0000x reference)
//
#include <hip/hip_runtime.h>

// SolarRNN: B=256, T=4096, F=16, H=64. Two fused GRU layers + online-softmax
// attention + MLP tail in ONE persistent kernel.
//
// R4: TWO sequences per block (512 thr, 8 waves): waves 0-3 = seq A, 4-7 =
// seq B, one wave of each seq per SIMD. The per-sequence schedule is R3's
// (unchanged, verified): 4 waves, K-split-4, quarter-density DPP reduction,
// 1 barrier/step. The co-resident independent wave hides the ~1250 cy/step
// of dependency stall R3 exposed at 1 wave/SIMD (measured 1958 cy/step vs
// ~700 issue cy). Block barrier is shared; both groups execute identical
// barrier counts. Grid = 128 blocks.

#define B_ 256
#define T_ 4096
#define F_ 16
#define H_ 64
#define L2E 1.4426950408889634f

__device__ __forceinline__ float rdlane(float v, int lane) {
    return __builtin_bit_cast(float, __builtin_amdgcn_readlane(__builtin_bit_cast(int, v), lane));
}
__device__ __forceinline__ float sigm(float x) {
    float e = __builtin_amdgcn_exp2f(-L2E * x);
    return __builtin_amdgcn_rcpf(1.0f + e);
}
__device__ __forceinline__ float tanh_(float x) {
    float e = __builtin_amdgcn_exp2f(2.0f * L2E * x);
    return 1.0f - 2.0f * __builtin_amdgcn_rcpf(1.0f + e);
}

#define DPPADD(x, ctrl) \
    ((x) + __builtin_bit_cast(float, __builtin_amdgcn_update_dpp( \
        0, __builtin_bit_cast(int, (x)), (ctrl), 0xF, 0xF, true)))

// sum across each quad of lanes; result in all 4 lanes of the quad
__device__ __forceinline__ float qsum(float x) {
    float s = DPPADD(x, 0xB1);   // quad_perm [1,0,3,2]
    return DPPADD(s, 0x4E);      // quad_perm [2,3,0,1]
}
// full wave64 sum; total lands in lane 63
__device__ __forceinline__ float wred(float x) {
    x = DPPADD(x, 0x111);        // row_shr:1
    x = DPPADD(x, 0x112);        // row_shr:2
    x = DPPADD(x, 0x114);        // row_shr:4
    x = DPPADD(x, 0x118);        // row_shr:8
    x = DPPADD(x, 0x142);        // row_bcast:15
    x = DPPADD(x, 0x143);        // row_bcast:31
    return x;
}

__launch_bounds__(512, 2)
__global__ void solar_rnn(const float* __restrict__ x,
                          const float* __restrict__ Wi1, const float* __restrict__ bi1,
                          const float* __restrict__ Whr1, const float* __restrict__ Whz1,
                          const float* __restrict__ Whn1, const float* __restrict__ bhn1,
                          const float* __restrict__ Wi2, const float* __restrict__ bi2,
                          const float* __restrict__ Whr2, const float* __restrict__ Whz2,
                          const float* __restrict__ Whn2, const float* __restrict__ bhn2,
                          const float* __restrict__ Wp, const float* __restrict__ bp,
                          const float* __restrict__ Wa,
                          const float* __restrict__ W1, const float* __restrict__ b1,
                          const float* __restrict__ W2, const float* __restrict__ b2,
                          const float* __restrict__ W3, const float* __restrict__ b3,
                          const float* __restrict__ W4, const float* __restrict__ b4,
                          float* __restrict__ out)
{
    const int tid = threadIdx.x;
    const int s   = tid >> 8;           // sequence slot within block (0/1)
    const int lt  = tid & 255;          // local tid within the seq group
    const int v   = lt >> 6;            // wave-within-seq 0..3 = k-slice
    const int j   = tid & 63;           // lane: FMA block -> output col j
    const int oj  = 16 * v + (j >> 2);  // quarter-density output index
    const int b   = blockIdx.x * 2 + s; // sequence index

    // per-seq: planes 0-8 partials (word = output*4 + slot), plane 9 p-partials
    __shared__ float red[2][2][10][256];
    __shared__ float sm_a[2][128];
    __shared__ float sm_b[2][128];

    const int wslot = (v + (j >> 3)) & 3;    // bijective per output, <=2-way banks
    const int widx  = 4 * j + wslot;
    const int ridx  = 64 * v + j;            // = o(j)*4 + (j&3), stride-1

    // ---- per-lane weight slices (column j, rows [16v,16v+16)) ----
    float wr1[16], wz1[16], wn1[16];
    float wr2[16], wz2[16], wn2[16];
    float u2r[16], u2z[16], u2n[16];
    #pragma unroll
    for (int k = 0; k < 16; ++k) {
        const int row = 16 * v + k;
        wr1[k] = Whr1[row * H_ + j];
        wz1[k] = Whz1[row * H_ + j];
        wn1[k] = Whn1[row * H_ + j];
        wr2[k] = Whr2[row * H_ + j];
        wz2[k] = Whz2[row * H_ + j];
        wn2[k] = Whn2[row * H_ + j];
        u2r[k] = Wi2[row * 192 + j];
        u2z[k] = Wi2[row * 192 + 64 + j];
        u2n[k] = Wi2[row * 192 + 128 + j];
    }
    float w1r[4], w1z[4], w1n[4], wpv[4], x2r[4], x2z[4], x2n[4];
    #pragma unroll
    for (int kk = 0; kk < 4; ++kk) {
        const int row = 4 * v + kk;
        w1r[kk] = Wi1[row * 192 + j];
        w1z[kk] = Wi1[row * 192 + 64 + j];
        w1n[kk] = Wi1[row * 192 + 128 + j];
        wpv[kk] = Wp[row * H_ + j];
        float ar = 0.f, az = 0.f, an = 0.f;
        for (int m = 0; m < H_; ++m) {
            const float wp = Wp[row * H_ + m];
            ar = fmaf(wp, Wi2[m * 192 + j],       ar);
            az = fmaf(wp, Wi2[m * 192 + 64 + j],  az);
            an = fmaf(wp, Wi2[m * 192 + 128 + j], an);
        }
        x2r[kk] = 0.5f * ar; x2z[kk] = 0.5f * az; x2n[kk] = 0.5f * an;
    }
    // ---- quarter-density (oj-indexed) biases ----
    float cbr = 0.f, cbz = 0.f, cbn = 0.f;
    for (int m = 0; m < H_; ++m) {
        const float bpm = bp[m];
        cbr = fmaf(bpm, Wi2[m * 192 + oj],       cbr);
        cbz = fmaf(bpm, Wi2[m * 192 + 64 + oj],  cbz);
        cbn = fmaf(bpm, Wi2[m * 192 + 128 + oj], cbn);
    }
    const float b1r = bi1[oj], b1z = bi1[64 + oj], b1n = bi1[128 + oj], bh1o = bhn1[oj];
    const float bb2r = bi2[oj]       + 0.5f * cbr;
    const float bb2z = bi2[64 + oj]  + 0.5f * cbz;
    const float bb2n = bi2[128 + oj] + 0.5f * cbn;
    const float bh2o = bhn2[oj];
    const float bpo  = bp[oj], wao = Wa[oj];
    // ba: softmax shift-invariant, skipped.

    float h1 = 0.f, h2 = 0.f, o1p = 0.f, o2a = 0.f;   // quarter-density state
    float am = -3.0e38f, al = 0.f, aa = 0.f;
    float sH1[16], sH2[16];
    #pragma unroll
    for (int k = 0; k < 16; ++k) { sH1[k] = 0.f; sH2[k] = 0.f; }

    const float* xb = x + (size_t)b * T_ * F_;
    float4 xq_cur  = *(const float4*)(xb + ((size_t)j * F_ + 4 * v));
    float4 xq_next = *(const float4*)(xb + ((size_t)(64 + j) * F_ + 4 * v));

    float cx0, cx1, cx2, cx3;   // x(t) scalars carried across iterations

    // ---- pro0: L1 x-partials(0) -> buf0 ----
    {
        const float a0 = rdlane(xq_cur.x, 0), a1 = rdlane(xq_cur.y, 0),
                    a2 = rdlane(xq_cur.z, 0), a3 = rdlane(xq_cur.w, 0);
        red[s][0][0][widx] = fmaf(a0, w1r[0], fmaf(a1, w1r[1], fmaf(a2, w1r[2], a3 * w1r[3])));
        red[s][0][1][widx] = fmaf(a0, w1z[0], fmaf(a1, w1z[1], fmaf(a2, w1z[2], a3 * w1z[3])));
        red[s][0][2][widx] = fmaf(a0, w1n[0], fmaf(a1, w1n[1], fmaf(a2, w1n[2], a3 * w1n[3])));
        red[s][0][3][widx] = 0.f;
        red[s][0][4][widx] = fmaf(a0, wpv[0], fmaf(a1, wpv[1], fmaf(a2, wpv[2], a3 * wpv[3])));
        cx0 = a0; cx1 = a1; cx2 = a2; cx3 = a3;
    }
    __syncthreads();

    // ---- pro1 (peeled step 0): h1(0); write L2(0)+L1(1) -> buf1 ----
    {
        float g0 = qsum(red[s][0][0][ridx]);
        float g1 = qsum(red[s][0][1][ridx]);
        float g2 = qsum(red[s][0][2][ridx]);
        float g3 = qsum(red[s][0][3][ridx]);
        float g4 = qsum(red[s][0][4][ridx]);
        const float r1 = sigm(g0 + b1r);
        const float z1 = sigm(g1 + b1z);
        const float n1 = tanh_((g2 + b1n) + r1 * (g3 + bh1o));
        h1 = n1 + z1 * (h1 - n1);
        o1p = h1 + 0.5f * (g4 + bpo);
        #pragma unroll
        for (int k = 0; k < 16; ++k) sH1[k] = rdlane(h1, 4 * k);

        const float xn0 = rdlane(xq_cur.x, 1), xn1 = rdlane(xq_cur.y, 1),
                    xn2 = rdlane(xq_cur.z, 1), xn3 = rdlane(xq_cur.w, 1);
        // L2(0) partials (h2(-1)=0)
        float ar2 = fmaf(cx0, x2r[0], fmaf(cx1, x2r[1], fmaf(cx2, x2r[2], cx3 * x2r[3])));
        float az2 = fmaf(cx0, x2z[0], fmaf(cx1, x2z[1], fmaf(cx2, x2z[2], cx3 * x2z[3])));
        float an2 = fmaf(cx0, x2n[0], fmaf(cx1, x2n[1], fmaf(cx2, x2n[2], cx3 * x2n[3])));
        #pragma unroll
        for (int k = 0; k < 16; ++k) {
            ar2 = fmaf(sH1[k], u2r[k], ar2);
            az2 = fmaf(sH1[k], u2z[k], az2);
            an2 = fmaf(sH1[k], u2n[k], an2);
        }
        red[s][1][5][widx] = ar2;
        red[s][1][6][widx] = az2;
        red[s][1][7][widx] = an2;
        red[s][1][8][widx] = 0.f;
        // L1(1) partials
        float ar1 = fmaf(xn0, w1r[0], fmaf(xn1, w1r[1], fmaf(xn2, w1r[2], xn3 * w1r[3])));
        float az1 = fmaf(xn0, w1z[0], fmaf(xn1, w1z[1], fmaf(xn2, w1z[2], xn3 * w1z[3])));
        float an1 = fmaf(xn0, w1n[0], fmaf(xn1, w1n[1], fmaf(xn2, w1n[2], xn3 * w1n[3])));
        float ax1 = fmaf(xn0, wpv[0], fmaf(xn1, wpv[1], fmaf(xn2, wpv[2], xn3 * wpv[3])));
        float hn1 = 0.f;
        #pragma unroll
        for (int k = 0; k < 16; ++k) {
            ar1 = fmaf(sH1[k], wr1[k], ar1);
            az1 = fmaf(sH1[k], wz1[k], az1);
            hn1 = fmaf(sH1[k], wn1[k], hn1);
        }
        red[s][1][0][widx] = ar1;
        red[s][1][1][widx] = az1;
        red[s][1][2][widx] = an1;
        red[s][1][3][widx] = hn1;
        red[s][1][4][widx] = ax1;
        cx0 = xn0; cx1 = xn1; cx2 = xn2; cx3 = xn3;
    }
    __syncthreads();

    // ---- main loop: iter t reduces L2(t-1)+L1(t), writes L2(t)+L1(t+1),
    //      softmax update for step t-2 (p-partials arrive 1 step late) ----
    #pragma unroll 1
    for (int t = 1; t < T_; ++t) {
        const int pb = t & 1, qb = pb ^ 1;
        const int u = t + 1;
        if ((u & 63) == 0) {
            xq_cur = xq_next;
            const int c = (u >> 6) + 1;
            if (c < T_ / 64)
                xq_next = *(const float4*)(xb + (size_t)(c * 64 + j) * F_ + 4 * v);
        }
        const int ul = u & 63;
        const float xn0 = rdlane(xq_cur.x, ul), xn1 = rdlane(xq_cur.y, ul),
                    xn2 = rdlane(xq_cur.z, ul), xn3 = rdlane(xq_cur.w, ul);

        const float* rp = &red[s][pb][0][0];
        float g0 = rp[0 * 256 + ridx], g1 = rp[1 * 256 + ridx], g2 = rp[2 * 256 + ridx];
        float g3 = rp[3 * 256 + ridx], g4 = rp[4 * 256 + ridx], g5 = rp[5 * 256 + ridx];
        float g6 = rp[6 * 256 + ridx], g7 = rp[7 * 256 + ridx], g8 = rp[8 * 256 + ridx];
        float gp = rp[9 * 256 + (j & 3)];
        g0 = qsum(g0); g1 = qsum(g1); g2 = qsum(g2); g3 = qsum(g3); g4 = qsum(g4);
        g5 = qsum(g5); g6 = qsum(g6); g7 = qsum(g7); g8 = qsum(g8); gp = qsum(gp);

        // softmax update for step t-2 (o2a = o2(t-2), gp = its score partials)
        if (t >= 2) {
            const float p  = 0.25f * gp;
            const float mn = fmaxf(am, p);
            const float ca = __builtin_amdgcn_exp2f((am - mn) * L2E);
            const float ce = __builtin_amdgcn_exp2f((p  - mn) * L2E);
            al = fmaf(al, ca, ce);
            aa = fmaf(aa, ca, ce * o2a);
            am = mn;
        }

        // ---- h2(t-1) + score partial ----
        const float r2 = sigm(g5 + bb2r);
        const float z2 = sigm(g6 + bb2z);
        const float n2 = tanh_((g7 + bb2n) + r2 * (g8 + bh2o));
        h2 = n2 + z2 * (h2 - n2);
        const float o2 = h2 + 0.5f * o1p;
        float ps = wred(o2 * wao);
        if (j == 63) red[s][qb][9][v] = ps;
        o2a = o2;
        #pragma unroll
        for (int k = 0; k < 16; ++k) sH2[k] = rdlane(h2, 4 * k);

        // ---- h1(t) ----
        const float r1 = sigm(g0 + b1r);
        const float z1 = sigm(g1 + b1z);
        const float n1 = tanh_((g2 + b1n) + r1 * (g3 + bh1o));
        h1 = n1 + z1 * (h1 - n1);
        o1p = h1 + 0.5f * (g4 + bpo);
        #pragma unroll
        for (int k = 0; k < 16; ++k) sH1[k] = rdlane(h1, 4 * k);

        // ---- FMA partials: L2(t) + L1(t+1) -> red[s][qb] ----
        float ar2 = fmaf(cx0, x2r[0], fmaf(cx1, x2r[1], fmaf(cx2, x2r[2], cx3 * x2r[3])));
        float az2 = fmaf(cx0, x2z[0], fmaf(cx1, x2z[1], fmaf(cx2, x2z[2], cx3 * x2z[3])));
        float an2 = fmaf(cx0, x2n[0], fmaf(cx1, x2n[1], fmaf(cx2, x2n[2], cx3 * x2n[3])));
        float hn2 = 0.f;
        #pragma unroll
        for (int k = 0; k < 16; ++k) {
            ar2 = fmaf(sH2[k], wr2[k], ar2);
            az2 = fmaf(sH2[k], wz2[k], az2);
            hn2 = fmaf(sH2[k], wn2[k], hn2);
        }
        #pragma unroll
        for (int k = 0; k < 16; ++k) {
            ar2 = fmaf(sH1[k], u2r[k], ar2);
            az2 = fmaf(sH1[k], u2z[k], az2);
            an2 = fmaf(sH1[k], u2n[k], an2);
        }
        float* wp_ = &red[s][qb][0][0];
        wp_[5 * 256 + widx] = ar2;
        wp_[6 * 256 + widx] = az2;
        wp_[7 * 256 + widx] = an2;
        wp_[8 * 256 + widx] = hn2;

        float ar1 = fmaf(xn0, w1r[0], fmaf(xn1, w1r[1], fmaf(xn2, w1r[2], xn3 * w1r[3])));
        float az1 = fmaf(xn0, w1z[0], fmaf(xn1, w1z[1], fmaf(xn2, w1z[2], xn3 * w1z[3])));
        float an1 = fmaf(xn0, w1n[0], fmaf(xn1, w1n[1], fmaf(xn2, w1n[2], xn3 * w1n[3])));
        float ax1 = fmaf(xn0, wpv[0], fmaf(xn1, wpv[1], fmaf(xn2, wpv[2], xn3 * wpv[3])));
        float hn1 = 0.f;
        #pragma unroll
        for (int k = 0; k < 16; ++k) {
            ar1 = fmaf(sH1[k], wr1[k], ar1);
            az1 = fmaf(sH1[k], wz1[k], az1);
            hn1 = fmaf(sH1[k], wn1[k], hn1);
        }
        wp_[0 * 256 + widx] = ar1;
        wp_[1 * 256 + widx] = az1;
        wp_[2 * 256 + widx] = an1;
        wp_[3 * 256 + widx] = hn1;
        wp_[4 * 256 + widx] = ax1;

        cx0 = xn0; cx1 = xn1; cx2 = xn2; cx3 = xn3;
        __syncthreads();
    }

    // ---- epilogue: pending steps T-2 and T-1 ----
    {
        // last iter (t=T-1, odd) wrote to buf 0
        const float* rp = &red[s][0][0][0];
        float g5 = qsum(rp[5 * 256 + ridx]);
        float g6 = qsum(rp[6 * 256 + ridx]);
        float g7 = qsum(rp[7 * 256 + ridx]);
        float g8 = qsum(rp[8 * 256 + ridx]);
        float gp = qsum(rp[9 * 256 + (j & 3)]);
        // softmax update (T-2): o2a = o2(T-2)
        {
            const float p  = 0.25f * gp;
            const float mn = fmaxf(am, p);
            const float ca = __builtin_amdgcn_exp2f((am - mn) * L2E);
            const float ce = __builtin_amdgcn_exp2f((p  - mn) * L2E);
            al = fmaf(al, ca, ce);
            aa = fmaf(aa, ca, ce * o2a);
            am = mn;
        }
        // h2(T-1)
        const float r2 = sigm(g5 + bb2r);
        const float z2 = sigm(g6 + bb2z);
        const float n2 = tanh_((g7 + bb2n) + r2 * (g8 + bh2o));
        h2 = n2 + z2 * (h2 - n2);
        const float o2 = h2 + 0.5f * o1p;
        float ps = wred(o2 * wao);
        if (j == 63) red[s][1][9][v] = ps;
        __syncthreads();
        float gq = qsum(red[s][1][9][j & 3]);
        {
            const float p  = 0.25f * gq;
            const float mn = fmaxf(am, p);
            const float ca = __builtin_amdgcn_exp2f((am - mn) * L2E);
            const float ce = __builtin_amdgcn_exp2f((p  - mn) * L2E);
            al = fmaf(al, ca, ce);
            aa = fmaf(aa, ca, ce * o2);
            am = mn;
        }
    }

    // ---- attended vector (quarter-density -> sm_a[s]) + MLP tail ----
    if ((j & 3) == 0) sm_a[s][oj] = aa / al;
    __syncthreads();

    float v1 = 0.f;
    if (lt < 128) {
        float a = b1[lt];
        for (int k = 0; k < 64; ++k) a = fmaf(sm_a[s][k], W1[k * 128 + lt], a);
        v1 = fmaxf(a, 0.f);
    }
    __syncthreads();
    if (lt < 128) sm_b[s][lt] = v1;
    __syncthreads();
    if (lt < 64) {
        float a = b2[lt];
        for (int k = 0; k < 128; ++k) a = fmaf(sm_b[s][k], W2[k * 64 + lt], a);
        sm_a[s][lt] = fmaxf(a, 0.f);
    }
    __syncthreads();
    if (lt < 32) {
        float a = b3[lt];
        for (int k = 0; k < 64; ++k) a = fmaf(sm_a[s][k], W3[k * 32 + lt], a);
        sm_b[s][lt] = fmaxf(a, 0.f);
    }
    __syncthreads();
    if (lt < 2) {
        float a = b4[lt];
        for (int k = 0; k < 32; ++k) a = fmaf(sm_b[s][k], W4[k * 2 + lt], a);
        out[b * 2 + lt] = a;
    }
}

extern "C" void kernel_launch(void* const* d_in, const int* in_sizes, int n_in,
                              void* d_out, int out_size, void* d_ws, size_t ws_size,
                              hipStream_t stream) {
    const float* x    = (const float*)d_in[0];
    const float* Wi1  = (const float*)d_in[1];
    const float* bi1  = (const float*)d_in[2];
    const float* Whr1 = (const float*)d_in[3];
    const float* Whz1 = (const float*)d_in[4];
    const float* Whn1 = (const float*)d_in[5];
    const float* bhn1 = (const float*)d_in[6];
    const float* Wi2  = (const float*)d_in[7];
    const float* bi2  = (const float*)d_in[8];
    const float* Whr2 = (const float*)d_in[9];
    const float* Whz2 = (const float*)d_in[10];
    const float* Whn2 = (const float*)d_in[11];
    const float* bhn2 = (const float*)d_in[12];
    const float* Wp   = (const float*)d_in[13];
    const float* bp   = (const float*)d_in[14];
    const float* Wa   = (const float*)d_in[15];
    // d_in[16] = ba: softmax shift-invariant, unused
    const float* W1   = (const float*)d_in[17];
    const float* b1   = (const float*)d_in[18];
    const float* W2   = (const float*)d_in[19];
    const float* b2   = (const float*)d_in[20];
    const float* W3   = (const float*)d_in[21];
    const float* b3   = (const float*)d_in[22];
    const float* W4   = (const float*)d_in[23];
    const float* b4   = (const float*)d_in[24];

    solar_rnn<<<dim3(B_ / 2), dim3(512), 0, stream>>>(
        x, Wi1, bi1, Whr1, Whz1, Whn1, bhn1,
        Wi2, bi2, Whr2, Whz2, Whn2, bhn2,
        Wp, bp, Wa, W1, b1, W2, b2, W3, b3, W4, b4,
        (float*)d_out);
}

// Round 5
// 3009.737 us; speedup vs baseline: 1.8822x; 1.8822x over previous
//
#include <hip/hip_runtime.h>

// SolarRNN: B=256, T=4096, F=16, H=64. Two fused GRU layers + online-softmax
// attention + MLP tail in ONE persistent kernel: block b = sequence b.
//
// R5 = R3's verified skeleton (4 waves, K-split-4, quarter-density DPP
// reduction, 1 barrier/step, slot-XOR conflict-free LDS) + issue-count cuts:
//  - v_pk_fma_f32 pairing over k: weights stored as float2 pairs, broadcast
//    scalars paired from the same readlanes, x scalars paired. FMA stream
//    172 -> ~86 pk + 9 horizontal adds.
//  - LDS planes paired: 9 accs -> 5 x b64 planes (10+10 b32 -> 5+5 b64;
//    write pattern 2-way bank aliased = free).
//  - Reads issued first; x-only partial chains (independent of LDS data)
//    placed immediately after to cover the ~120cy LDS latency.
// Schedule, qsum, wred, pipeline skew, softmax staging: UNCHANGED from R3.

#define B_ 256
#define T_ 4096
#define F_ 16
#define H_ 64
#define L2E 1.4426950408889634f

typedef float v2f __attribute__((ext_vector_type(2)));

__device__ __forceinline__ float rdlane(float v, int lane) {
    return __builtin_bit_cast(float, __builtin_amdgcn_readlane(__builtin_bit_cast(int, v), lane));
}
__device__ __forceinline__ float sigm(float x) {
    float e = __builtin_amdgcn_exp2f(-L2E * x);
    return __builtin_amdgcn_rcpf(1.0f + e);
}
__device__ __forceinline__ float tanh_(float x) {
    float e = __builtin_amdgcn_exp2f(2.0f * L2E * x);
    return 1.0f - 2.0f * __builtin_amdgcn_rcpf(1.0f + e);
}
__device__ __forceinline__ v2f fma2(v2f a, v2f b, v2f c) {
    return __builtin_elementwise_fma(a, b, c);
}

#define DPPADD(x, ctrl) \
    ((x) + __builtin_bit_cast(float, __builtin_amdgcn_update_dpp( \
        0, __builtin_bit_cast(int, (x)), (ctrl), 0xF, 0xF, true)))

// sum across each quad of lanes; result in all 4 lanes of the quad
__device__ __forceinline__ float qsum(float x) {
    float s = DPPADD(x, 0xB1);   // quad_perm [1,0,3,2]
    return DPPADD(s, 0x4E);      // quad_perm [2,3,0,1]
}
// full wave64 sum; total lands in lane 63 (verified in R3 - do not touch)
__device__ __forceinline__ float wred(float x) {
    x = DPPADD(x, 0x111);        // row_shr:1
    x = DPPADD(x, 0x112);        // row_shr:2
    x = DPPADD(x, 0x114);        // row_shr:4
    x = DPPADD(x, 0x118);        // row_shr:8
    x = DPPADD(x, 0x142);        // row_bcast:15
    x = DPPADD(x, 0x143);        // row_bcast:31
    return x;
}

__launch_bounds__(256, 1)
__global__ void solar_rnn(const float* __restrict__ x,
                          const float* __restrict__ Wi1, const float* __restrict__ bi1,
                          const float* __restrict__ Whr1, const float* __restrict__ Whz1,
                          const float* __restrict__ Whn1, const float* __restrict__ bhn1,
                          const float* __restrict__ Wi2, const float* __restrict__ bi2,
                          const float* __restrict__ Whr2, const float* __restrict__ Whz2,
                          const float* __restrict__ Whn2, const float* __restrict__ bhn2,
                          const float* __restrict__ Wp, const float* __restrict__ bp,
                          const float* __restrict__ Wa,
                          const float* __restrict__ W1, const float* __restrict__ b1,
                          const float* __restrict__ W2, const float* __restrict__ b2,
                          const float* __restrict__ W3, const float* __restrict__ b3,
                          const float* __restrict__ W4, const float* __restrict__ b4,
                          float* __restrict__ out)
{
    const int b   = blockIdx.x;
    const int tid = threadIdx.x;
    const int v   = tid >> 6;        // wave 0..3 = k-slice (rows [16v,16v+16))
    const int j   = tid & 63;        // lane: FMA block -> output col j
    const int oj  = 16 * v + (j >> 2);  // quarter-density output index

    // paired planes: plane p holds accs (2p, 2p+1) as b64 words.
    // acc order: 0=ar1 1=az1 | 2=an1 3=hn1 | 4=ax1 5=an2 | 6=ar2 7=az2 | 8=hn2 9=pad
    __shared__ __align__(16) float red[2][5][256][2];
    __shared__ float sp[2][64];          // score partials (plane-9 equivalent)
    __shared__ float sm_a[128];
    __shared__ float sm_b[128];

    const int wslot = (v + (j >> 3)) & 3;    // bijective per output, <=2-way banks
    const int widx  = 4 * j + wslot;
    const int ridx  = 64 * v + j;            // = o(j)*4 + (j&3), stride-1

    // ---- per-lane weight PAIRS (column j, rows [16v,16v+16) paired over k) ----
    v2f wr1p[8], wz1p[8], wn1p[8];
    v2f wr2p[8], wz2p[8], wn2p[8];
    v2f u2rp[8], u2zp[8], u2np[8];
    #pragma unroll
    for (int m = 0; m < 8; ++m) {
        const int r0 = 16 * v + 2 * m, r1 = r0 + 1;
        wr1p[m] = v2f{Whr1[r0 * H_ + j], Whr1[r1 * H_ + j]};
        wz1p[m] = v2f{Whz1[r0 * H_ + j], Whz1[r1 * H_ + j]};
        wn1p[m] = v2f{Whn1[r0 * H_ + j], Whn1[r1 * H_ + j]};
        wr2p[m] = v2f{Whr2[r0 * H_ + j], Whr2[r1 * H_ + j]};
        wz2p[m] = v2f{Whz2[r0 * H_ + j], Whz2[r1 * H_ + j]};
        wn2p[m] = v2f{Whn2[r0 * H_ + j], Whn2[r1 * H_ + j]};
        u2rp[m] = v2f{Wi2[r0 * 192 + j],       Wi2[r1 * 192 + j]};
        u2zp[m] = v2f{Wi2[r0 * 192 + 64 + j],  Wi2[r1 * 192 + 64 + j]};
        u2np[m] = v2f{Wi2[r0 * 192 + 128 + j], Wi2[r1 * 192 + 128 + j]};
    }
    float x2r[4], x2z[4], x2n[4];
    #pragma unroll
    for (int kk = 0; kk < 4; ++kk) {
        const int row = 4 * v + kk;
        float ar = 0.f, az = 0.f, an = 0.f;
        for (int m = 0; m < H_; ++m) {
            const float wp = Wp[row * H_ + m];
            ar = fmaf(wp, Wi2[m * 192 + j],       ar);
            az = fmaf(wp, Wi2[m * 192 + 64 + j],  az);
            an = fmaf(wp, Wi2[m * 192 + 128 + j], an);
        }
        x2r[kk] = 0.5f * ar; x2z[kk] = 0.5f * az; x2n[kk] = 0.5f * an;
    }
    v2f w1rp[2], w1zp[2], w1np[2], wpvp[2], x2rp[2], x2zp[2], x2np[2];
    #pragma unroll
    for (int m = 0; m < 2; ++m) {
        const int r0 = 4 * v + 2 * m, r1 = r0 + 1;
        w1rp[m] = v2f{Wi1[r0 * 192 + j],       Wi1[r1 * 192 + j]};
        w1zp[m] = v2f{Wi1[r0 * 192 + 64 + j],  Wi1[r1 * 192 + 64 + j]};
        w1np[m] = v2f{Wi1[r0 * 192 + 128 + j], Wi1[r1 * 192 + 128 + j]};
        wpvp[m] = v2f{Wp[r0 * H_ + j],         Wp[r1 * H_ + j]};
        x2rp[m] = v2f{x2r[2 * m], x2r[2 * m + 1]};
        x2zp[m] = v2f{x2z[2 * m], x2z[2 * m + 1]};
        x2np[m] = v2f{x2n[2 * m], x2n[2 * m + 1]};
    }
    // ---- quarter-density (oj-indexed) biases ----
    float cbr = 0.f, cbz = 0.f, cbn = 0.f;
    for (int m = 0; m < H_; ++m) {
        const float bpm = bp[m];
        cbr = fmaf(bpm, Wi2[m * 192 + oj],       cbr);
        cbz = fmaf(bpm, Wi2[m * 192 + 64 + oj],  cbz);
        cbn = fmaf(bpm, Wi2[m * 192 + 128 + oj], cbn);
    }
    const float b1r = bi1[oj], b1z = bi1[64 + oj], b1n = bi1[128 + oj], bh1o = bhn1[oj];
    const float bb2r = bi2[oj]       + 0.5f * cbr;
    const float bb2z = bi2[64 + oj]  + 0.5f * cbz;
    const float bb2n = bi2[128 + oj] + 0.5f * cbn;
    const float bh2o = bhn2[oj];
    const float bpo  = bp[oj], wao = Wa[oj];
    // ba: softmax shift-invariant, skipped.

    float h1 = 0.f, h2 = 0.f, o1p = 0.f, o2a = 0.f;   // quarter-density state
    float am = -3.0e38f, al = 0.f, aa = 0.f;
    v2f sH1p[8], sH2p[8];                // uniform broadcast pairs (from readlanes)
    #pragma unroll
    for (int m = 0; m < 8; ++m) { sH1p[m] = v2f{0.f, 0.f}; sH2p[m] = v2f{0.f, 0.f}; }

    const float* xb = x + (size_t)b * T_ * F_;
    float4 xq_cur  = *(const float4*)(xb + ((size_t)j * F_ + 4 * v));
    float4 xq_next = *(const float4*)(xb + ((size_t)(64 + j) * F_ + 4 * v));

    v2f cxp0, cxp1;   // x(t) scalar pairs carried across iterations (uniform)

    // ---- pro0: L1 x-partials(0) -> buf0 ----
    {
        const float a0 = rdlane(xq_cur.x, 0), a1 = rdlane(xq_cur.y, 0),
                    a2 = rdlane(xq_cur.z, 0), a3 = rdlane(xq_cur.w, 0);
        const v2f ap0 = v2f{a0, a1}, ap1 = v2f{a2, a3};
        const v2f zz = v2f{0.f, 0.f};
        v2f arp = fma2(w1rp[0], ap0, fma2(w1rp[1], ap1, zz));
        v2f azp = fma2(w1zp[0], ap0, fma2(w1zp[1], ap1, zz));
        v2f anp = fma2(w1np[0], ap0, fma2(w1np[1], ap1, zz));
        v2f axp = fma2(wpvp[0], ap0, fma2(wpvp[1], ap1, zz));
        *(v2f*)&red[0][0][widx][0] = v2f{arp.x + arp.y, azp.x + azp.y};
        *(v2f*)&red[0][1][widx][0] = v2f{anp.x + anp.y, 0.f};
        *(v2f*)&red[0][2][widx][0] = v2f{axp.x + axp.y, 0.f};
        cxp0 = ap0; cxp1 = ap1;
    }
    __syncthreads();

    // ---- pro1 (peeled step 0): h1(0); write L2(0)+L1(1) -> buf1 ----
    {
        const v2f q0 = *(const v2f*)&red[0][0][ridx][0];
        const v2f q1 = *(const v2f*)&red[0][1][ridx][0];
        const v2f q2 = *(const v2f*)&red[0][2][ridx][0];
        const float g0 = qsum(q0.x), g1 = qsum(q0.y);
        const float g2 = qsum(q1.x), g3 = qsum(q1.y);
        const float g4 = qsum(q2.x);
        const float r1 = sigm(g0 + b1r);
        const float z1 = sigm(g1 + b1z);
        const float n1 = tanh_((g2 + b1n) + r1 * (g3 + bh1o));
        h1 = n1 + z1 * (h1 - n1);
        o1p = h1 + 0.5f * (g4 + bpo);
        #pragma unroll
        for (int m = 0; m < 8; ++m)
            sH1p[m] = v2f{rdlane(h1, 8 * m), rdlane(h1, 8 * m + 4)};

        const float xn0 = rdlane(xq_cur.x, 1), xn1 = rdlane(xq_cur.y, 1),
                    xn2 = rdlane(xq_cur.z, 1), xn3 = rdlane(xq_cur.w, 1);
        const v2f xp0 = v2f{xn0, xn1}, xp1 = v2f{xn2, xn3};
        const v2f zz = v2f{0.f, 0.f};

        // L2(0) partials (h2(-1)=0)
        v2f Aar2 = fma2(x2rp[0], cxp0, fma2(x2rp[1], cxp1, zz));
        v2f Aaz2 = fma2(x2zp[0], cxp0, fma2(x2zp[1], cxp1, zz));
        v2f Aan2 = fma2(x2np[0], cxp0, fma2(x2np[1], cxp1, zz));
        #pragma unroll
        for (int m = 0; m < 8; ++m) {
            Aar2 = fma2(sH1p[m], u2rp[m], Aar2);
            Aaz2 = fma2(sH1p[m], u2zp[m], Aaz2);
            Aan2 = fma2(sH1p[m], u2np[m], Aan2);
        }
        // L1(1) partials
        v2f Aar1 = fma2(w1rp[0], xp0, fma2(w1rp[1], xp1, zz));
        v2f Aaz1 = fma2(w1zp[0], xp0, fma2(w1zp[1], xp1, zz));
        v2f Aan1 = fma2(w1np[0], xp0, fma2(w1np[1], xp1, zz));
        v2f Aax1 = fma2(wpvp[0], xp0, fma2(wpvp[1], xp1, zz));
        v2f Ahn1 = zz;
        #pragma unroll
        for (int m = 0; m < 8; ++m) {
            Aar1 = fma2(sH1p[m], wr1p[m], Aar1);
            Aaz1 = fma2(sH1p[m], wz1p[m], Aaz1);
            Ahn1 = fma2(sH1p[m], wn1p[m], Ahn1);
        }
        *(v2f*)&red[1][0][widx][0] = v2f{Aar1.x + Aar1.y, Aaz1.x + Aaz1.y};
        *(v2f*)&red[1][1][widx][0] = v2f{Aan1.x + Aan1.y, Ahn1.x + Ahn1.y};
        *(v2f*)&red[1][2][widx][0] = v2f{Aax1.x + Aax1.y, Aan2.x + Aan2.y};
        *(v2f*)&red[1][3][widx][0] = v2f{Aar2.x + Aar2.y, Aaz2.x + Aaz2.y};
        *(v2f*)&red[1][4][widx][0] = v2f{0.f, 0.f};
        cxp0 = xp0; cxp1 = xp1;
    }
    __syncthreads();

    // ---- main loop: iter t reduces L2(t-1)+L1(t), writes L2(t)+L1(t+1),
    //      softmax update for step t-2 (p-partials arrive 1 step late) ----
    #pragma unroll 1
    for (int t = 1; t < T_; ++t) {
        const int pb = t & 1, qb = pb ^ 1;
        const int u = t + 1;
        if ((u & 63) == 0) {
            xq_cur = xq_next;
            const int c = (u >> 6) + 1;
            if (c < T_ / 64)
                xq_next = *(const float4*)(xb + (size_t)(c * 64 + j) * F_ + 4 * v);
        }
        const int ul = u & 63;
        const v2f xp0 = v2f{rdlane(xq_cur.x, ul), rdlane(xq_cur.y, ul)};
        const v2f xp1 = v2f{rdlane(xq_cur.z, ul), rdlane(xq_cur.w, ul)};

        // LDS reads first (5 x b64 + score word) ...
        const v2f q0 = *(const v2f*)&red[pb][0][ridx][0];
        const v2f q1 = *(const v2f*)&red[pb][1][ridx][0];
        const v2f q2 = *(const v2f*)&red[pb][2][ridx][0];
        const v2f q3 = *(const v2f*)&red[pb][3][ridx][0];
        const v2f q4 = *(const v2f*)&red[pb][4][ridx][0];
        float gp = sp[pb][j & 3];

        // ... then x-only partial chains (independent of the reads -> hides latency)
        const v2f zz = v2f{0.f, 0.f};
        v2f Aar1 = fma2(w1rp[0], xp0, fma2(w1rp[1], xp1, zz));
        v2f Aaz1 = fma2(w1zp[0], xp0, fma2(w1zp[1], xp1, zz));
        v2f Aan1 = fma2(w1np[0], xp0, fma2(w1np[1], xp1, zz));
        v2f Aax1 = fma2(wpvp[0], xp0, fma2(wpvp[1], xp1, zz));
        v2f Aar2 = fma2(x2rp[0], cxp0, fma2(x2rp[1], cxp1, zz));
        v2f Aaz2 = fma2(x2zp[0], cxp0, fma2(x2zp[1], cxp1, zz));
        v2f Aan2 = fma2(x2np[0], cxp0, fma2(x2np[1], cxp1, zz));
        v2f Ahn1 = zz, Ahn2 = zz;

        const float g0 = qsum(q0.x), g1 = qsum(q0.y);
        const float g2 = qsum(q1.x), g3 = qsum(q1.y);
        const float g4 = qsum(q2.x), g5 = qsum(q2.y);   // ax1, an2
        const float g6 = qsum(q3.x), g7 = qsum(q3.y);   // ar2, az2
        const float g8 = qsum(q4.x);                    // hn2
        gp = qsum(gp);

        // softmax update for step t-2 (o2a = o2(t-2), gp = its score partials)
        if (t >= 2) {
            const float p  = 0.25f * gp;
            const float mn = fmaxf(am, p);
            const float ca = __builtin_amdgcn_exp2f((am - mn) * L2E);
            const float ce = __builtin_amdgcn_exp2f((p  - mn) * L2E);
            al = fmaf(al, ca, ce);
            aa = fmaf(aa, ca, ce * o2a);
            am = mn;
        }

        // ---- h2(t-1) + score partial ----
        const float r2 = sigm(g6 + bb2r);
        const float z2 = sigm(g7 + bb2z);
        const float n2 = tanh_((g5 + bb2n) + r2 * (g8 + bh2o));
        h2 = n2 + z2 * (h2 - n2);
        const float o2 = h2 + 0.5f * o1p;
        float ps = wred(o2 * wao);
        if (j == 63) sp[qb][v] = ps;
        o2a = o2;
        #pragma unroll
        for (int m = 0; m < 8; ++m)
            sH2p[m] = v2f{rdlane(h2, 8 * m), rdlane(h2, 8 * m + 4)};

        // ---- h1(t) ----
        const float r1 = sigm(g0 + b1r);
        const float z1 = sigm(g1 + b1z);
        const float n1 = tanh_((g2 + b1n) + r1 * (g3 + bh1o));
        h1 = n1 + z1 * (h1 - n1);
        o1p = h1 + 0.5f * (g4 + bpo);
        #pragma unroll
        for (int m = 0; m < 8; ++m)
            sH1p[m] = v2f{rdlane(h1, 8 * m), rdlane(h1, 8 * m + 4)};

        // ---- recurrent pk-FMA block: L2(t) + L1(t+1) ----
        #pragma unroll
        for (int m = 0; m < 8; ++m) {
            Aar2 = fma2(sH2p[m], wr2p[m], Aar2);
            Aaz2 = fma2(sH2p[m], wz2p[m], Aaz2);
            Ahn2 = fma2(sH2p[m], wn2p[m], Ahn2);
        }
        #pragma unroll
        for (int m = 0; m < 8; ++m) {
            Aar2 = fma2(sH1p[m], u2rp[m], Aar2);
            Aaz2 = fma2(sH1p[m], u2zp[m], Aaz2);
            Aan2 = fma2(sH1p[m], u2np[m], Aan2);
        }
        #pragma unroll
        for (int m = 0; m < 8; ++m) {
            Aar1 = fma2(sH1p[m], wr1p[m], Aar1);
            Aaz1 = fma2(sH1p[m], wz1p[m], Aaz1);
            Ahn1 = fma2(sH1p[m], wn1p[m], Ahn1);
        }

        *(v2f*)&red[qb][0][widx][0] = v2f{Aar1.x + Aar1.y, Aaz1.x + Aaz1.y};
        *(v2f*)&red[qb][1][widx][0] = v2f{Aan1.x + Aan1.y, Ahn1.x + Ahn1.y};
        *(v2f*)&red[qb][2][widx][0] = v2f{Aax1.x + Aax1.y, Aan2.x + Aan2.y};
        *(v2f*)&red[qb][3][widx][0] = v2f{Aar2.x + Aar2.y, Aaz2.x + Aaz2.y};
        *(v2f*)&red[qb][4][widx][0] = v2f{Ahn2.x + Ahn2.y, 0.f};

        cxp0 = xp0; cxp1 = xp1;
        __syncthreads();
    }

    // ---- epilogue: pending steps T-2 and T-1 ----
    {
        // last iter (t=T-1, odd) wrote to buf 0
        const v2f q2 = *(const v2f*)&red[0][2][ridx][0];
        const v2f q3 = *(const v2f*)&red[0][3][ridx][0];
        const v2f q4 = *(const v2f*)&red[0][4][ridx][0];
        const float g5 = qsum(q2.y);
        const float g6 = qsum(q3.x), g7 = qsum(q3.y);
        const float g8 = qsum(q4.x);
        float gp = qsum(sp[0][j & 3]);
        // softmax update (T-2): o2a = o2(T-2)
        {
            const float p  = 0.25f * gp;
            const float mn = fmaxf(am, p);
            const float ca = __builtin_amdgcn_exp2f((am - mn) * L2E);
            const float ce = __builtin_amdgcn_exp2f((p  - mn) * L2E);
            al = fmaf(al, ca, ce);
            aa = fmaf(aa, ca, ce * o2a);
            am = mn;
        }
        // h2(T-1)
        const float r2 = sigm(g6 + bb2r);
        const float z2 = sigm(g7 + bb2z);
        const float n2 = tanh_((g5 + bb2n) + r2 * (g8 + bh2o));
        h2 = n2 + z2 * (h2 - n2);
        const float o2 = h2 + 0.5f * o1p;
        float ps = wred(o2 * wao);
        if (j == 63) sp[1][v] = ps;
        __syncthreads();
        float gq = qsum(sp[1][j & 3]);
        {
            const float p  = 0.25f * gq;
            const float mn = fmaxf(am, p);
            const float ca = __builtin_amdgcn_exp2f((am - mn) * L2E);
            const float ce = __builtin_amdgcn_exp2f((p  - mn) * L2E);
            al = fmaf(al, ca, ce);
            aa = fmaf(aa, ca, ce * o2);
            am = mn;
        }
    }

    // ---- attended vector (quarter-density -> sm_a) + MLP tail ----
    if ((j & 3) == 0) sm_a[oj] = aa / al;
    __syncthreads();

    float v1 = 0.f;
    if (tid < 128) {
        float a = b1[tid];
        for (int k = 0; k < 64; ++k) a = fmaf(sm_a[k], W1[k * 128 + tid], a);
        v1 = fmaxf(a, 0.f);
    }
    __syncthreads();
    if (tid < 128) sm_b[tid] = v1;
    __syncthreads();
    if (tid < 64) {
        float a = b2[tid];
        for (int k = 0; k < 128; ++k) a = fmaf(sm_b[k], W2[k * 64 + tid], a);
        sm_a[tid] = fmaxf(a, 0.f);
    }
    __syncthreads();
    if (tid < 32) {
        float a = b3[tid];
        for (int k = 0; k < 64; ++k) a = fmaf(sm_a[k], W3[k * 32 + tid], a);
        sm_b[tid] = fmaxf(a, 0.f);
    }
    __syncthreads();
    if (tid < 2) {
        float a = b4[tid];
        for (int k = 0; k < 32; ++k) a = fmaf(sm_b[k], W4[k * 2 + tid], a);
        out[b * 2 + tid] = a;
    }
}

extern "C" void kernel_launch(void* const* d_in, const int* in_sizes, int n_in,
                              void* d_out, int out_size, void* d_ws, size_t ws_size,
                              hipStream_t stream) {
    const float* x    = (const float*)d_in[0];
    const float* Wi1  = (const float*)d_in[1];
    const float* bi1  = (const float*)d_in[2];
    const float* Whr1 = (const float*)d_in[3];
    const float* Whz1 = (const float*)d_in[4];
    const float* Whn1 = (const float*)d_in[5];
    const float* bhn1 = (const float*)d_in[6];
    const float* Wi2  = (const float*)d_in[7];
    const float* bi2  = (const float*)d_in[8];
    const float* Whr2 = (const float*)d_in[9];
    const float* Whz2 = (const float*)d_in[10];
    const float* Whn2 = (const float*)d_in[11];
    const float* bhn2 = (const float*)d_in[12];
    const float* Wp   = (const float*)d_in[13];
    const float* bp   = (const float*)d_in[14];
    const float* Wa   = (const float*)d_in[15];
    // d_in[16] = ba: softmax shift-invariant, unused
    const float* W1   = (const float*)d_in[17];
    const float* b1   = (const float*)d_in[18];
    const float* W2   = (const float*)d_in[19];
    const float* b2   = (const float*)d_in[20];
    const float* W3   = (const float*)d_in[21];
    const float* b3   = (const float*)d_in[22];
    const float* W4   = (const float*)d_in[23];
    const float* b4   = (const float*)d_in[24];

    solar_rnn<<<dim3(B_), dim3(256), 0, stream>>>(
        x, Wi1, bi1, Whr1, Whz1, Whn1, bhn1,
        Wi2, bi2, Whr2, Whz2, Whn2, bhn2,
        Wp, bp, Wa, W1, b1, W2, b2, W3, b3, W4, b4,
        (float*)d_out);
}

// Round 6
// 2619.470 us; speedup vs baseline: 2.1627x; 1.1490x over previous
//
#include <hip/hip_runtime.h>

// SolarRNN: B=256, T=4096, F=16, H=64. Two fused GRU layers + online-softmax
// attention + MLP tail in ONE persistent kernel: block b = sequence b.
//
// R6: communication transposed. Lane = (o = j>>2, s = j&3): output 16v+o,
// k-slice [16s,16s+16). Gate K-reduction is INTRA-QUAD (verified qsum, 2 DPP)
// -- the 9-plane partials LDS all-to-all (R3/R5's 10 write + 10 read + qsum
// per step) is GONE. Cross-wave traffic is only h1(t), h2(t-1): 2 b32 writes
// (s==0 lanes), 8 rotated conflict-free broadcast ds_read_b128. The 32
// v_readlane h-broadcasts are gone too (h arrives as VGPR pairs for pk_fma).
// x is read per-s-group from a 16-step LDS chunk buffer staged by wave 0.
// Rotation trick: read-slot q fetches rows 16s+4qq (qq=(q+s)&3) and the
// WEIGHT registers are loaded with the same permutation, so all array
// indices stay compile-time (no scratch). Skew schedule (iter t: h1(t) +
// h2(t-1), softmax applies p(t-2)), qsum/wred, guards: from verified R3/R5.

#define B_ 256
#define T_ 4096
#define F_ 16
#define H_ 64
#define L2E 1.4426950408889634f

typedef float v2f __attribute__((ext_vector_type(2)));

__device__ __forceinline__ float sigm(float x) {
    float e = __builtin_amdgcn_exp2f(-L2E * x);
    return __builtin_amdgcn_rcpf(1.0f + e);
}
__device__ __forceinline__ float tanh_(float x) {
    float e = __builtin_amdgcn_exp2f(2.0f * L2E * x);
    return 1.0f - 2.0f * __builtin_amdgcn_rcpf(1.0f + e);
}
__device__ __forceinline__ v2f fma2(v2f a, v2f b, v2f c) {
    return __builtin_elementwise_fma(a, b, c);
}

#define DPPADD(x, ctrl) \
    ((x) + __builtin_bit_cast(float, __builtin_amdgcn_update_dpp( \
        0, __builtin_bit_cast(int, (x)), (ctrl), 0xF, 0xF, true)))

// sum across each quad of lanes; result in all 4 lanes of the quad
__device__ __forceinline__ float qsum(float x) {
    float t = DPPADD(x, 0xB1);   // quad_perm [1,0,3,2]
    return DPPADD(t, 0x4E);      // quad_perm [2,3,0,1]
}
// full wave64 sum; total lands in lane 63
__device__ __forceinline__ float wred(float x) {
    x = DPPADD(x, 0x111);        // row_shr:1
    x = DPPADD(x, 0x112);        // row_shr:2
    x = DPPADD(x, 0x114);        // row_shr:4
    x = DPPADD(x, 0x118);        // row_shr:8
    x = DPPADD(x, 0x142);        // row_bcast:15
    x = DPPADD(x, 0x143);        // row_bcast:31
    return x;
}

__launch_bounds__(256, 1)
__global__ void solar_rnn(const float* __restrict__ x,
                          const float* __restrict__ Wi1, const float* __restrict__ bi1,
                          const float* __restrict__ Whr1, const float* __restrict__ Whz1,
                          const float* __restrict__ Whn1, const float* __restrict__ bhn1,
                          const float* __restrict__ Wi2, const float* __restrict__ bi2,
                          const float* __restrict__ Whr2, const float* __restrict__ Whz2,
                          const float* __restrict__ Whn2, const float* __restrict__ bhn2,
                          const float* __restrict__ Wp, const float* __restrict__ bp,
                          const float* __restrict__ Wa,
                          const float* __restrict__ W1, const float* __restrict__ b1,
                          const float* __restrict__ W2, const float* __restrict__ b2,
                          const float* __restrict__ W3, const float* __restrict__ b3,
                          const float* __restrict__ W4, const float* __restrict__ b4,
                          float* __restrict__ out)
{
    const int b   = blockIdx.x;
    const int tid = threadIdx.x;
    const int v   = tid >> 6;        // wave 0..3
    const int j   = tid & 63;
    const int o   = j >> 2;          // output-within-wave 0..15
    const int s   = j & 3;           // k-slice: rows [16s, 16s+16)
    const int col = 16 * v + o;      // this lane's output column

    __shared__ __align__(16) float h1p[2][H_];
    __shared__ __align__(16) float h2p[2][H_];
    __shared__ __align__(16) float xbuf[2][256];   // [chunk parity][16 steps x 16]
    __shared__ float spl[2][4];                    // score partials per wave
    __shared__ float sm_a[128];
    __shared__ float sm_b[128];

    // ---- rotated read offsets (loop-invariant): slot q -> rows 16s+4qq ----
    int hoff[4];
    #pragma unroll
    for (int q = 0; q < 4; ++q) hoff[q] = 16 * s + 4 * ((q + s) & 3);

    // ---- weights, loaded with the SAME rotation as the h-reads ----
    v2f wr1p[8], wz1p[8], wn1p[8];
    v2f wr2p[8], wz2p[8], wn2p[8];
    v2f u2rp[8], u2zp[8], u2np[8];
    #pragma unroll
    for (int q = 0; q < 4; ++q) {
        const int rb = hoff[q];
        #pragma unroll
        for (int e = 0; e < 2; ++e) {
            const int r0 = rb + 2 * e, r1 = r0 + 1;
            const int m = 2 * q + e;
            wr1p[m] = v2f{Whr1[r0 * H_ + col], Whr1[r1 * H_ + col]};
            wz1p[m] = v2f{Whz1[r0 * H_ + col], Whz1[r1 * H_ + col]};
            wn1p[m] = v2f{Whn1[r0 * H_ + col], Whn1[r1 * H_ + col]};
            wr2p[m] = v2f{Whr2[r0 * H_ + col], Whr2[r1 * H_ + col]};
            wz2p[m] = v2f{Whz2[r0 * H_ + col], Whz2[r1 * H_ + col]};
            wn2p[m] = v2f{Whn2[r0 * H_ + col], Whn2[r1 * H_ + col]};
            u2rp[m] = v2f{Wi2[r0 * 192 + col],       Wi2[r1 * 192 + col]};
            u2zp[m] = v2f{Wi2[r0 * 192 + 64 + col],  Wi2[r1 * 192 + 64 + col]};
            u2np[m] = v2f{Wi2[r0 * 192 + 128 + col], Wi2[r1 * 192 + 128 + col]};
        }
    }
    // x-projection weights (k in [4s,4s+4), no rotation needed)
    float x2r[4], x2z[4], x2n[4];
    #pragma unroll
    for (int kk = 0; kk < 4; ++kk) {
        const int row = 4 * s + kk;
        float ar = 0.f, az = 0.f, an = 0.f;
        for (int m = 0; m < H_; ++m) {
            const float wp = Wp[row * H_ + m];
            ar = fmaf(wp, Wi2[m * 192 + col],       ar);
            az = fmaf(wp, Wi2[m * 192 + 64 + col],  az);
            an = fmaf(wp, Wi2[m * 192 + 128 + col], an);
        }
        x2r[kk] = 0.5f * ar; x2z[kk] = 0.5f * az; x2n[kk] = 0.5f * an;
    }
    v2f w1rp[2], w1zp[2], w1np[2], wpvp[2], x2rp[2], x2zp[2], x2np[2];
    #pragma unroll
    for (int m = 0; m < 2; ++m) {
        const int r0 = 4 * s + 2 * m, r1 = r0 + 1;
        w1rp[m] = v2f{Wi1[r0 * 192 + col],       Wi1[r1 * 192 + col]};
        w1zp[m] = v2f{Wi1[r0 * 192 + 64 + col],  Wi1[r1 * 192 + 64 + col]};
        w1np[m] = v2f{Wi1[r0 * 192 + 128 + col], Wi1[r1 * 192 + 128 + col]};
        wpvp[m] = v2f{Wp[r0 * H_ + col],         Wp[r1 * H_ + col]};
        x2rp[m] = v2f{x2r[2 * m], x2r[2 * m + 1]};
        x2zp[m] = v2f{x2z[2 * m], x2z[2 * m + 1]};
        x2np[m] = v2f{x2n[2 * m], x2n[2 * m + 1]};
    }
    // biases (output-col indexed); fold bp@Wi2 into L2 gate biases
    float cbr = 0.f, cbz = 0.f, cbn = 0.f;
    for (int m = 0; m < H_; ++m) {
        const float bpm = bp[m];
        cbr = fmaf(bpm, Wi2[m * 192 + col],       cbr);
        cbz = fmaf(bpm, Wi2[m * 192 + 64 + col],  cbz);
        cbn = fmaf(bpm, Wi2[m * 192 + 128 + col], cbn);
    }
    const float b1r = bi1[col], b1z = bi1[64 + col], b1n = bi1[128 + col], bh1o = bhn1[col];
    const float bb2r = bi2[col]       + 0.5f * cbr;
    const float bb2z = bi2[64 + col]  + 0.5f * cbz;
    const float bb2n = bi2[128 + col] + 0.5f * cbn;
    const float bh2o = bhn2[col];
    const float bpo  = bp[col], wao = Wa[col];
    // ba: softmax shift-invariant, skipped.

    // ---- init LDS: zero h planes + score partials; stage x chunk 0 ----
    if (tid < 64) { h1p[0][j] = 0.f; h1p[1][j] = 0.f; h2p[0][j] = 0.f; h2p[1][j] = 0.f; }
    if (tid < 8)  spl[tid >> 2][tid & 3] = 0.f;
    const float* xb = x + (size_t)b * T_ * F_;
    float4 xnext;
    if (tid < 64) {
        const float4* gx = (const float4*)xb;
        ((float4*)xbuf[0])[j] = gx[j];     // chunk 0
        xnext = gx[64 + j];                // chunk 1 (written at t=8)
    }
    __syncthreads();

    float h1 = 0.f, h2 = 0.f, o1p = 0.f, o2a = 0.f;
    float am = -3.0e38f, al = 0.f, aa = 0.f;
    v2f xprev0 = v2f{0.f, 0.f}, xprev1 = v2f{0.f, 0.f};

    #pragma unroll 1
    for (int t = 0; t < T_; ++t) {
        const int tb = t & 1;

        // ---- LDS reads: x(t), h1(t-1), h2(t-2), score partials ----
        const float4 xt4 = ((const float4*)xbuf[(t >> 4) & 1])[(t & 15) * 4 + s];
        const float* h1r = h1p[tb ^ 1];
        const float* h2r = h2p[tb];
        v2f hv1[8], hv2[8];
        #pragma unroll
        for (int q = 0; q < 4; ++q) {
            const float4 a = *(const float4*)&h1r[hoff[q]];
            const float4 c = *(const float4*)&h2r[hoff[q]];
            hv1[2 * q]     = v2f{a.x, a.y};
            hv1[2 * q + 1] = v2f{a.z, a.w};
            hv2[2 * q]     = v2f{c.x, c.y};
            hv2[2 * q + 1] = v2f{c.z, c.w};
        }
        float gp = spl[tb][s];

        // ---- gate partials (per-lane, k in [16s,16s+16)) ----
        const v2f zz = v2f{0.f, 0.f};
        // L2 x-terms use carried x(t-1)
        v2f Aar2 = fma2(x2rp[0], xprev0, fma2(x2rp[1], xprev1, zz));
        v2f Aaz2 = fma2(x2zp[0], xprev0, fma2(x2zp[1], xprev1, zz));
        v2f Aan2 = fma2(x2np[0], xprev0, fma2(x2np[1], xprev1, zz));
        // L1 x-terms use x(t)
        const v2f xt0 = v2f{xt4.x, xt4.y}, xt1 = v2f{xt4.z, xt4.w};
        v2f Aar1 = fma2(w1rp[0], xt0, fma2(w1rp[1], xt1, zz));
        v2f Aaz1 = fma2(w1zp[0], xt0, fma2(w1zp[1], xt1, zz));
        v2f Aan1 = fma2(w1np[0], xt0, fma2(w1np[1], xt1, zz));
        v2f Aax1 = fma2(wpvp[0], xt0, fma2(wpvp[1], xt1, zz));
        v2f Ahn1 = zz, Ahn2 = zz;
        #pragma unroll
        for (int m = 0; m < 8; ++m) {
            Aar1 = fma2(hv1[m], wr1p[m], Aar1);
            Aaz1 = fma2(hv1[m], wz1p[m], Aaz1);
            Ahn1 = fma2(hv1[m], wn1p[m], Ahn1);
            Aar2 = fma2(hv1[m], u2rp[m], Aar2);
            Aaz2 = fma2(hv1[m], u2zp[m], Aaz2);
            Aan2 = fma2(hv1[m], u2np[m], Aan2);
            Aar2 = fma2(hv2[m], wr2p[m], Aar2);
            Aaz2 = fma2(hv2[m], wz2p[m], Aaz2);
            Ahn2 = fma2(hv2[m], wn2p[m], Ahn2);
        }
        // ---- intra-quad reduction (replaces the LDS partials round-trip) ----
        const float g0 = qsum(Aar1.x + Aar1.y);
        const float g1 = qsum(Aaz1.x + Aaz1.y);
        const float g2 = qsum(Aan1.x + Aan1.y);
        const float g3 = qsum(Ahn1.x + Ahn1.y);
        const float g4 = qsum(Aax1.x + Aax1.y);
        const float g5 = qsum(Aan2.x + Aan2.y);
        const float g6 = qsum(Aar2.x + Aar2.y);
        const float g7 = qsum(Aaz2.x + Aaz2.y);
        const float g8 = qsum(Ahn2.x + Ahn2.y);
        gp = qsum(gp);

        // ---- softmax apply for step t-2 ----
        if (t >= 2) {
            const float p  = 0.25f * gp;
            const float mn = fmaxf(am, p);
            const float ca = __builtin_amdgcn_exp2f((am - mn) * L2E);
            const float ce = __builtin_amdgcn_exp2f((p  - mn) * L2E);
            al = fmaf(al, ca, ce);
            aa = fmaf(aa, ca, ce * o2a);
            am = mn;
        }

        // ---- L2 pointwise: h2(t-1) ----
        const float r2 = sigm(g6 + bb2r);
        const float z2 = sigm(g7 + bb2z);
        const float n2 = tanh_((g5 + bb2n) + r2 * (g8 + bh2o));
        h2 = n2 + z2 * (h2 - n2);
        h2 = (t == 0) ? 0.f : h2;            // h2(-1) := 0
        const float o2 = h2 + 0.5f * o1p;    // o1p = o1(t-1)
        float ps = wred(o2 * wao);
        if (j == 63) spl[tb ^ 1][v] = ps;
        if (s == 0) h2p[tb ^ 1][col] = h2;
        o2a = o2;

        // ---- L1 pointwise: h1(t) ----
        const float r1 = sigm(g0 + b1r);
        const float z1 = sigm(g1 + b1z);
        const float n1 = tanh_((g2 + b1n) + r1 * (g3 + bh1o));
        h1 = n1 + z1 * (h1 - n1);
        o1p = h1 + 0.5f * (g4 + bpo);
        if (s == 0) h1p[tb][col] = h1;

        // ---- x chunk staging (wave 0, mid-chunk) ----
        if ((t & 15) == 8 && tid < 64) {
            const int c = t >> 4;
            if (c + 1 < T_ / 16) {
                ((float4*)xbuf[(c + 1) & 1])[j] = xnext;
                if (c + 2 < T_ / 16) xnext = ((const float4*)xb)[(c + 2) * 64 + j];
            }
        }
        xprev0 = xt0; xprev1 = xt1;
        __syncthreads();
    }

    // ---- epilogue: L2(T-1) + last two softmax contributions ----
    {
        const float* h1r = h1p[1];           // h1(T-1), T-1 odd
        const float* h2r = h2p[0];           // h2(T-2)
        v2f hv1[8], hv2[8];
        #pragma unroll
        for (int q = 0; q < 4; ++q) {
            const float4 a = *(const float4*)&h1r[hoff[q]];
            const float4 c = *(const float4*)&h2r[hoff[q]];
            hv1[2 * q]     = v2f{a.x, a.y};
            hv1[2 * q + 1] = v2f{a.z, a.w};
            hv2[2 * q]     = v2f{c.x, c.y};
            hv2[2 * q + 1] = v2f{c.z, c.w};
        }
        const v2f zz = v2f{0.f, 0.f};
        v2f Aar2 = fma2(x2rp[0], xprev0, fma2(x2rp[1], xprev1, zz));
        v2f Aaz2 = fma2(x2zp[0], xprev0, fma2(x2zp[1], xprev1, zz));
        v2f Aan2 = fma2(x2np[0], xprev0, fma2(x2np[1], xprev1, zz));
        v2f Ahn2 = zz;
        #pragma unroll
        for (int m = 0; m < 8; ++m) {
            Aar2 = fma2(hv1[m], u2rp[m], Aar2);
            Aaz2 = fma2(hv1[m], u2zp[m], Aaz2);
            Aan2 = fma2(hv1[m], u2np[m], Aan2);
            Aar2 = fma2(hv2[m], wr2p[m], Aar2);
            Aaz2 = fma2(hv2[m], wz2p[m], Aaz2);
            Ahn2 = fma2(hv2[m], wn2p[m], Ahn2);
        }
        const float g5 = qsum(Aan2.x + Aan2.y);
        const float g6 = qsum(Aar2.x + Aar2.y);
        const float g7 = qsum(Aaz2.x + Aaz2.y);
        const float g8 = qsum(Ahn2.x + Ahn2.y);
        float gp = qsum(spl[0][s]);          // p(T-2): written at t=T-1 (tb=1 -> spl[0])
        {
            const float p  = 0.25f * gp;
            const float mn = fmaxf(am, p);
            const float ca = __builtin_amdgcn_exp2f((am - mn) * L2E);
            const float ce = __builtin_amdgcn_exp2f((p  - mn) * L2E);
            al = fmaf(al, ca, ce);
            aa = fmaf(aa, ca, ce * o2a);
            am = mn;
        }
        const float r2 = sigm(g6 + bb2r);
        const float z2 = sigm(g7 + bb2z);
        const float n2 = tanh_((g5 + bb2n) + r2 * (g8 + bh2o));
        h2 = n2 + z2 * (h2 - n2);
        const float o2 = h2 + 0.5f * o1p;
        float ps = wred(o2 * wao);
        if (j == 63) spl[1][v] = ps;
        __syncthreads();
        float gq = qsum(spl[1][s]);
        {
            const float p  = 0.25f * gq;
            const float mn = fmaxf(am, p);
            const float ca = __builtin_amdgcn_exp2f((am - mn) * L2E);
            const float ce = __builtin_amdgcn_exp2f((p  - mn) * L2E);
            al = fmaf(al, ca, ce);
            aa = fmaf(aa, ca, ce * o2);
            am = mn;
        }
    }

    // ---- attended vector + MLP tail ----
    if (s == 0) sm_a[col] = aa / al;
    __syncthreads();

    float v1 = 0.f;
    if (tid < 128) {
        float a = b1[tid];
        for (int k = 0; k < 64; ++k) a = fmaf(sm_a[k], W1[k * 128 + tid], a);
        v1 = fmaxf(a, 0.f);
    }
    __syncthreads();
    if (tid < 128) sm_b[tid] = v1;
    __syncthreads();
    if (tid < 64) {
        float a = b2[tid];
        for (int k = 0; k < 128; ++k) a = fmaf(sm_b[k], W2[k * 64 + tid], a);
        sm_a[tid] = fmaxf(a, 0.f);
    }
    __syncthreads();
    if (tid < 32) {
        float a = b3[tid];
        for (int k = 0; k < 64; ++k) a = fmaf(sm_a[k], W3[k * 32 + tid], a);
        sm_b[tid] = fmaxf(a, 0.f);
    }
    __syncthreads();
    if (tid < 2) {
        float a = b4[tid];
        for (int k = 0; k < 32; ++k) a = fmaf(sm_b[k], W4[k * 2 + tid], a);
        out[b * 2 + tid] = a;
    }
}

extern "C" void kernel_launch(void* const* d_in, const int* in_sizes, int n_in,
                              void* d_out, int out_size, void* d_ws, size_t ws_size,
                              hipStream_t stream) {
    const float* x    = (const float*)d_in[0];
    const float* Wi1  = (const float*)d_in[1];
    const float* bi1  = (const float*)d_in[2];
    const float* Whr1 = (const float*)d_in[3];
    const float* Whz1 = (const float*)d_in[4];
    const float* Whn1 = (const float*)d_in[5];
    const float* bhn1 = (const float*)d_in[6];
    const float* Wi2  = (const float*)d_in[7];
    const float* bi2  = (const float*)d_in[8];
    const float* Whr2 = (const float*)d_in[9];
    const float* Whz2 = (const float*)d_in[10];
    const float* Whn2 = (const float*)d_in[11];
    const float* bhn2 = (const float*)d_in[12];
    const float* Wp   = (const float*)d_in[13];
    const float* bp   = (const float*)d_in[14];
    const float* Wa   = (const float*)d_in[15];
    // d_in[16] = ba: softmax shift-invariant, unused
    const float* W1   = (const float*)d_in[17];
    const float* b1   = (const float*)d_in[18];
    const float* W2   = (const float*)d_in[19];
    const float* b2   = (const float*)d_in[20];
    const float* W3   = (const float*)d_in[21];
    const float* b3   = (const float*)d_in[22];
    const float* W4   = (const float*)d_in[23];
    const float* b4   = (const float*)d_in[24];

    solar_rnn<<<dim3(B_), dim3(256), 0, stream>>>(
        x, Wi1, bi1, Whr1, Whz1, Whn1, bhn1,
        Wi2, bi2, Whr2, Whz2, Whn2, bhn2,
        Wp, bp, Wa, W1, b1, W2, b2, W3, b3, W4, b4,
        (float*)d_out);
}

// Round 7
// 2420.460 us; speedup vs baseline: 2.3405x; 1.0822x over previous
//
#include <hip/hip_runtime.h>

// SolarRNN: B=256, T=4096, F=16, H=64. Two fused GRU layers + online-softmax
// attention + MLP tail in ONE persistent kernel: block b = sequence b.
//
// R7 = R6's h-exchange skeleton + ROLE-SPLIT across 8 waves (2 per SIMD):
//   waves 0-3 (L1-role): own h1/o1. Lane (o=j>>2, s=j&3), col=16v+o,
//     k-slice [16s,16s+16). 32 pk-FMA, 5 qsum, L1 pointwise, writes
//     h1[col], o1[col] (s==0 lanes, conflict-free b32).
//   waves 4-7 (L2-role): own h2/softmax/attention. Reads h1(t-1), o1(t-1)
//     (written by L1 LAST iter -> R6's skew, no new pipeline depth),
//     x(t-1) from xbuf, h2(t-2) own. 54 pk-FMA, 4 qsum, L2 pointwise,
//     wred score, online softmax (applies step t-2).
// One shared __syncthreads per step (textually single, all 8 waves).
// Each SIMD hosts one L1 + one L2 wave -> mutual stall hiding (R4 showed
// ~18% overlap even convoyed; R2's failure causes - partials all-to-all
// conflicts + redundant pointwise - are gone with h-exchange).
// Weight regs share names across roles (hw0..hw5, xw0..xw3, c0..c4) so the
// allocator overlaps them; only the executing role's values are ever read.

#define B_ 256
#define T_ 4096
#define F_ 16
#define H_ 64
#define L2E 1.4426950408889634f

typedef float v2f __attribute__((ext_vector_type(2)));

__device__ __forceinline__ float sigm(float x) {
    float e = __builtin_amdgcn_exp2f(-L2E * x);
    return __builtin_amdgcn_rcpf(1.0f + e);
}
__device__ __forceinline__ float tanh_(float x) {
    float e = __builtin_amdgcn_exp2f(2.0f * L2E * x);
    return 1.0f - 2.0f * __builtin_amdgcn_rcpf(1.0f + e);
}
__device__ __forceinline__ v2f fma2(v2f a, v2f b, v2f c) {
    return __builtin_elementwise_fma(a, b, c);
}

#define DPPADD(x, ctrl) \
    ((x) + __builtin_bit_cast(float, __builtin_amdgcn_update_dpp( \
        0, __builtin_bit_cast(int, (x)), (ctrl), 0xF, 0xF, true)))

// sum across each quad of lanes; result in all 4 lanes of the quad
__device__ __forceinline__ float qsum(float x) {
    float t = DPPADD(x, 0xB1);   // quad_perm [1,0,3,2]
    return DPPADD(t, 0x4E);      // quad_perm [2,3,0,1]
}
// full wave64 sum; total lands in lane 63
__device__ __forceinline__ float wred(float x) {
    x = DPPADD(x, 0x111);        // row_shr:1
    x = DPPADD(x, 0x112);        // row_shr:2
    x = DPPADD(x, 0x114);        // row_shr:4
    x = DPPADD(x, 0x118);        // row_shr:8
    x = DPPADD(x, 0x142);        // row_bcast:15
    x = DPPADD(x, 0x143);        // row_bcast:31
    return x;
}

__launch_bounds__(512, 1)
__global__ void solar_rnn(const float* __restrict__ x,
                          const float* __restrict__ Wi1, const float* __restrict__ bi1,
                          const float* __restrict__ Whr1, const float* __restrict__ Whz1,
                          const float* __restrict__ Whn1, const float* __restrict__ bhn1,
                          const float* __restrict__ Wi2, const float* __restrict__ bi2,
                          const float* __restrict__ Whr2, const float* __restrict__ Whz2,
                          const float* __restrict__ Whn2, const float* __restrict__ bhn2,
                          const float* __restrict__ Wp, const float* __restrict__ bp,
                          const float* __restrict__ Wa,
                          const float* __restrict__ W1, const float* __restrict__ b1,
                          const float* __restrict__ W2, const float* __restrict__ b2,
                          const float* __restrict__ W3, const float* __restrict__ b3,
                          const float* __restrict__ W4, const float* __restrict__ b4,
                          float* __restrict__ out)
{
    const int b   = blockIdx.x;
    const int tid = threadIdx.x;
    const int w   = tid >> 6;        // wave 0..7
    const int j   = tid & 63;
    const bool l2r = (w >= 4);       // role: 0-3 = L1, 4-7 = L2
    const int v   = w & 3;           // wave index within role
    const int o   = j >> 2;          // output-within-wave 0..15
    const int s   = j & 3;           // k-slice: rows [16s, 16s+16)
    const int col = 16 * v + o;      // this lane's output column

    __shared__ float h1p[2][H_];
    __shared__ float h2p[2][H_];
    __shared__ float o1pl[2][H_];
    __shared__ __align__(16) float xbuf[2][256];   // [chunk parity][16 steps x 16]
    __shared__ float spl[2][4];                    // score partials per L2 wave
    __shared__ float sm_a[128];
    __shared__ float sm_b[128];

    // rotated read offsets: slot q -> rows 16s + 4*((q+s)&3)
    int hoff[4];
    #pragma unroll
    for (int q = 0; q < 4; ++q) hoff[q] = 16 * s + 4 * ((q + s) & 3);

    // ---- role-shared weight registers ----
    // L1: hw0=Whr1 hw1=Whz1 hw2=Whn1 (hw3..5 unused)
    //     xw0=Wi1r xw1=Wi1z xw2=Wi1n xw3=Wp ; c0..c4 = bi1r,bi1z,bi1n,bhn1,bp
    // L2: hw0=Whr2 hw1=Whz2 hw2=Whn2 hw3=u2r hw4=u2z hw5=u2n
    //     xw0=x2r xw1=x2z xw2=x2n (xw3 unused) ; c0..c4 = bb2r,bb2z,bb2n,bhn2,Wa
    v2f hw0[8], hw1[8], hw2[8], hw3[8], hw4[8], hw5[8];
    v2f xw0[2], xw1[2], xw2[2], xw3[2];
    float c0, c1, c2, c3, c4;

    if (!l2r) {
        #pragma unroll
        for (int q = 0; q < 4; ++q) {
            const int rb = hoff[q];
            #pragma unroll
            for (int e = 0; e < 2; ++e) {
                const int r0 = rb + 2 * e, r1 = r0 + 1, m = 2 * q + e;
                hw0[m] = v2f{Whr1[r0 * H_ + col], Whr1[r1 * H_ + col]};
                hw1[m] = v2f{Whz1[r0 * H_ + col], Whz1[r1 * H_ + col]};
                hw2[m] = v2f{Whn1[r0 * H_ + col], Whn1[r1 * H_ + col]};
            }
        }
        #pragma unroll
        for (int m = 0; m < 2; ++m) {
            const int r0 = 4 * s + 2 * m, r1 = r0 + 1;
            xw0[m] = v2f{Wi1[r0 * 192 + col],       Wi1[r1 * 192 + col]};
            xw1[m] = v2f{Wi1[r0 * 192 + 64 + col],  Wi1[r1 * 192 + 64 + col]};
            xw2[m] = v2f{Wi1[r0 * 192 + 128 + col], Wi1[r1 * 192 + 128 + col]};
            xw3[m] = v2f{Wp[r0 * H_ + col],         Wp[r1 * H_ + col]};
        }
        c0 = bi1[col]; c1 = bi1[64 + col]; c2 = bi1[128 + col];
        c3 = bhn1[col]; c4 = bp[col];
    } else {
        #pragma unroll
        for (int q = 0; q < 4; ++q) {
            const int rb = hoff[q];
            #pragma unroll
            for (int e = 0; e < 2; ++e) {
                const int r0 = rb + 2 * e, r1 = r0 + 1, m = 2 * q + e;
                hw0[m] = v2f{Whr2[r0 * H_ + col], Whr2[r1 * H_ + col]};
                hw1[m] = v2f{Whz2[r0 * H_ + col], Whz2[r1 * H_ + col]};
                hw2[m] = v2f{Whn2[r0 * H_ + col], Whn2[r1 * H_ + col]};
                hw3[m] = v2f{Wi2[r0 * 192 + col],       Wi2[r1 * 192 + col]};
                hw4[m] = v2f{Wi2[r0 * 192 + 64 + col],  Wi2[r1 * 192 + 64 + col]};
                hw5[m] = v2f{Wi2[r0 * 192 + 128 + col], Wi2[r1 * 192 + 128 + col]};
            }
        }
        // x2 = 0.5 * (Wp @ Wi2), rows 4s..4s+4, col-indexed
        float x2r[4], x2z[4], x2n[4];
        #pragma unroll
        for (int kk = 0; kk < 4; ++kk) {
            const int row = 4 * s + kk;
            float ar = 0.f, az = 0.f, an = 0.f;
            for (int m = 0; m < H_; ++m) {
                const float wp = Wp[row * H_ + m];
                ar = fmaf(wp, Wi2[m * 192 + col],       ar);
                az = fmaf(wp, Wi2[m * 192 + 64 + col],  az);
                an = fmaf(wp, Wi2[m * 192 + 128 + col], an);
            }
            x2r[kk] = 0.5f * ar; x2z[kk] = 0.5f * az; x2n[kk] = 0.5f * an;
        }
        #pragma unroll
        for (int m = 0; m < 2; ++m) {
            xw0[m] = v2f{x2r[2 * m], x2r[2 * m + 1]};
            xw1[m] = v2f{x2z[2 * m], x2z[2 * m + 1]};
            xw2[m] = v2f{x2n[2 * m], x2n[2 * m + 1]};
        }
        // fold bp @ Wi2 into L2 gate biases
        float cbr = 0.f, cbz = 0.f, cbn = 0.f;
        for (int m = 0; m < H_; ++m) {
            const float bpm = bp[m];
            cbr = fmaf(bpm, Wi2[m * 192 + col],       cbr);
            cbz = fmaf(bpm, Wi2[m * 192 + 64 + col],  cbz);
            cbn = fmaf(bpm, Wi2[m * 192 + 128 + col], cbn);
        }
        c0 = bi2[col]       + 0.5f * cbr;
        c1 = bi2[64 + col]  + 0.5f * cbz;
        c2 = bi2[128 + col] + 0.5f * cbn;
        c3 = bhn2[col]; c4 = Wa[col];
        // ba: softmax shift-invariant, skipped.
    }

    // ---- init LDS + stage x chunk 0 (wave 0) ----
    if (tid < 64) {
        h1p[0][j] = 0.f; h1p[1][j] = 0.f;
        h2p[0][j] = 0.f; h2p[1][j] = 0.f;
        o1pl[0][j] = 0.f; o1pl[1][j] = 0.f;
    }
    if (tid < 8) spl[tid >> 2][tid & 3] = 0.f;
    const float* xb = x + (size_t)b * T_ * F_;
    float4 xnext;
    if (tid < 64) {
        const float4* gx = (const float4*)xb;
        ((float4*)xbuf[0])[j] = gx[j];     // chunk 0
        xnext = gx[64 + j];                // chunk 1 (written at t=8)
    }
    __syncthreads();

    float hS = 0.f;                        // L1: h1[col] | L2: h2[col]
    float o2a = 0.f;
    float am = -3.0e38f, al = 0.f, aa = 0.f;
    const v2f zz = v2f{0.f, 0.f};

    #pragma unroll 1
    for (int t = 0; t < T_; ++t) {
        const int tb = t & 1;
        if (!l2r) {
            // ================= L1-role: h1(t), o1(t) =================
            const float4 xt4 = ((const float4*)xbuf[(t >> 4) & 1])[(t & 15) * 4 + s];
            const float* h1r = h1p[tb ^ 1];
            v2f hv[8];
            #pragma unroll
            for (int q = 0; q < 4; ++q) {
                const float4 a = *(const float4*)&h1r[hoff[q]];
                hv[2 * q]     = v2f{a.x, a.y};
                hv[2 * q + 1] = v2f{a.z, a.w};
            }
            const v2f xt0 = v2f{xt4.x, xt4.y}, xt1 = v2f{xt4.z, xt4.w};
            v2f Ar = fma2(xw0[0], xt0, fma2(xw0[1], xt1, zz));
            v2f Az = fma2(xw1[0], xt0, fma2(xw1[1], xt1, zz));
            v2f An = fma2(xw2[0], xt0, fma2(xw2[1], xt1, zz));
            v2f Ax = fma2(xw3[0], xt0, fma2(xw3[1], xt1, zz));
            v2f Ah = zz;
            #pragma unroll
            for (int m = 0; m < 8; ++m) {
                Ar = fma2(hv[m], hw0[m], Ar);
                Az = fma2(hv[m], hw1[m], Az);
                Ah = fma2(hv[m], hw2[m], Ah);
            }
            const float g0 = qsum(Ar.x + Ar.y);
            const float g1 = qsum(Az.x + Az.y);
            const float g2 = qsum(An.x + An.y);
            const float g3 = qsum(Ah.x + Ah.y);
            const float g4 = qsum(Ax.x + Ax.y);
            const float r1 = sigm(g0 + c0);
            const float z1 = sigm(g1 + c1);
            const float n1 = tanh_((g2 + c2) + r1 * (g3 + c3));
            hS = n1 + z1 * (hS - n1);
            const float o1 = hS + 0.5f * (g4 + c4);
            if (s == 0) { h1p[tb][col] = hS; o1pl[tb][col] = o1; }
            // x chunk staging (wave 0, mid-chunk)
            if ((t & 15) == 8 && w == 0) {
                const int c = t >> 4;
                if (c + 1 < T_ / 16) {
                    ((float4*)xbuf[(c + 1) & 1])[j] = xnext;
                    if (c + 2 < T_ / 16) xnext = ((const float4*)xb)[(c + 2) * 64 + j];
                }
            }
        } else {
            // ================= L2-role: h2(t-1), softmax(t-2) =================
            v2f xm0 = zz, xm1 = zz;
            if (t >= 1) {
                const int tm = t - 1;
                const float4 xm4 = ((const float4*)xbuf[(tm >> 4) & 1])[(tm & 15) * 4 + s];
                xm0 = v2f{xm4.x, xm4.y}; xm1 = v2f{xm4.z, xm4.w};
            }
            const float* h1r = h1p[tb ^ 1];    // h1(t-1), written by L1 last iter
            const float* h2r = h2p[tb];        // h2(t-2), own write last iter
            v2f hv[8], gv[8];
            #pragma unroll
            for (int q = 0; q < 4; ++q) {
                const float4 a = *(const float4*)&h1r[hoff[q]];
                const float4 c = *(const float4*)&h2r[hoff[q]];
                hv[2 * q]     = v2f{a.x, a.y};
                hv[2 * q + 1] = v2f{a.z, a.w};
                gv[2 * q]     = v2f{c.x, c.y};
                gv[2 * q + 1] = v2f{c.z, c.w};
            }
            const float o1r = o1pl[tb ^ 1][col];   // o1(t-1)
            float gp = spl[tb][s];                 // score partials of o2(t-2)

            v2f Ar = fma2(xw0[0], xm0, fma2(xw0[1], xm1, zz));
            v2f Az = fma2(xw1[0], xm0, fma2(xw1[1], xm1, zz));
            v2f An = fma2(xw2[0], xm0, fma2(xw2[1], xm1, zz));
            v2f Ah = zz;
            #pragma unroll
            for (int m = 0; m < 8; ++m) {
                Ar = fma2(gv[m], hw0[m], Ar);   // Whr2 . h2
                Az = fma2(gv[m], hw1[m], Az);
                Ah = fma2(gv[m], hw2[m], Ah);
                Ar = fma2(hv[m], hw3[m], Ar);   // u2r . h1
                Az = fma2(hv[m], hw4[m], Az);
                An = fma2(hv[m], hw5[m], An);
            }
            const float g6 = qsum(Ar.x + Ar.y);
            const float g7 = qsum(Az.x + Az.y);
            const float g5 = qsum(An.x + An.y);
            const float g8 = qsum(Ah.x + Ah.y);
            gp = qsum(gp);

            // softmax apply for step t-2
            if (t >= 2) {
                const float p  = 0.25f * gp;
                const float mn = fmaxf(am, p);
                const float ca = __builtin_amdgcn_exp2f((am - mn) * L2E);
                const float ce = __builtin_amdgcn_exp2f((p  - mn) * L2E);
                al = fmaf(al, ca, ce);
                aa = fmaf(aa, ca, ce * o2a);
                am = mn;
            }

            const float r2 = sigm(g6 + c0);
            const float z2 = sigm(g7 + c1);
            const float n2 = tanh_((g5 + c2) + r2 * (g8 + c3));
            hS = n2 + z2 * (hS - n2);
            hS = (t == 0) ? 0.f : hS;          // h2(-1) := 0
            const float o2 = hS + 0.5f * o1r;
            float ps = wred(o2 * c4);          // c4 = Wa[col]
            if (j == 63) spl[tb ^ 1][v] = ps;
            if (s == 0) h2p[tb ^ 1][col] = hS;
            o2a = o2;
        }
        __syncthreads();
    }

    // ---- epilogue: h2(T-1) + softmax for steps T-2, T-1 (L2 waves) ----
    if (l2r) {
        const int tm = T_ - 1;
        const float4 xm4 = ((const float4*)xbuf[(tm >> 4) & 1])[(tm & 15) * 4 + s];
        const v2f xm0 = v2f{xm4.x, xm4.y}, xm1 = v2f{xm4.z, xm4.w};
        const float* h1r = h1p[1];         // h1(T-1) (T-1 odd)
        const float* h2r = h2p[0];         // h2(T-2) (written at t=T-1 -> h2p[0])
        v2f hv[8], gv[8];
        #pragma unroll
        for (int q = 0; q < 4; ++q) {
            const float4 a = *(const float4*)&h1r[hoff[q]];
            const float4 c = *(const float4*)&h2r[hoff[q]];
            hv[2 * q]     = v2f{a.x, a.y};
            hv[2 * q + 1] = v2f{a.z, a.w};
            gv[2 * q]     = v2f{c.x, c.y};
            gv[2 * q + 1] = v2f{c.z, c.w};
        }
        const float o1r = o1pl[1][col];    // o1(T-1)
        v2f Ar = fma2(xw0[0], xm0, fma2(xw0[1], xm1, zz));
        v2f Az = fma2(xw1[0], xm0, fma2(xw1[1], xm1, zz));
        v2f An = fma2(xw2[0], xm0, fma2(xw2[1], xm1, zz));
        v2f Ah = zz;
        #pragma unroll
        for (int m = 0; m < 8; ++m) {
            Ar = fma2(gv[m], hw0[m], Ar);
            Az = fma2(gv[m], hw1[m], Az);
            Ah = fma2(gv[m], hw2[m], Ah);
            Ar = fma2(hv[m], hw3[m], Ar);
            Az = fma2(hv[m], hw4[m], Az);
            An = fma2(hv[m], hw5[m], An);
        }
        const float g6 = qsum(Ar.x + Ar.y);
        const float g7 = qsum(Az.x + Az.y);
        const float g5 = qsum(An.x + An.y);
        const float g8 = qsum(Ah.x + Ah.y);
        float gp = qsum(spl[0][s]);        // ps(T-2), written at t=T-1
        {
            const float p  = 0.25f * gp;
            const float mn = fmaxf(am, p);
            const float ca = __builtin_amdgcn_exp2f((am - mn) * L2E);
            const float ce = __builtin_amdgcn_exp2f((p  - mn) * L2E);
            al = fmaf(al, ca, ce);
            aa = fmaf(aa, ca, ce * o2a);
            am = mn;
        }
        const float r2 = sigm(g6 + c0);
        const float z2 = sigm(g7 + c1);
        const float n2 = tanh_((g5 + c2) + r2 * (g8 + c3));
        hS = n2 + z2 * (hS - n2);
        const float o2 = hS + 0.5f * o1r;  // o2(T-1)
        float ps = wred(o2 * c4);
        if (j == 63) spl[1][v] = ps;
        o2a = o2;
    }
    __syncthreads();
    if (l2r) {
        float gq = qsum(spl[1][s]);
        const float p  = 0.25f * gq;
        const float mn = fmaxf(am, p);
        const float ca = __builtin_amdgcn_exp2f((am - mn) * L2E);
        const float ce = __builtin_amdgcn_exp2f((p  - mn) * L2E);
        al = fmaf(al, ca, ce);
        aa = fmaf(aa, ca, ce * o2a);
        if (s == 0) sm_a[col] = aa / al;   // attended vector
    }
    __syncthreads();

    // ---- MLP tail (once per block) ----
    float v1 = 0.f;
    if (tid < 128) {
        float a = b1[tid];
        for (int k = 0; k < 64; ++k) a = fmaf(sm_a[k], W1[k * 128 + tid], a);
        v1 = fmaxf(a, 0.f);
    }
    __syncthreads();
    if (tid < 128) sm_b[tid] = v1;
    __syncthreads();
    if (tid < 64) {
        float a = b2[tid];
        for (int k = 0; k < 128; ++k) a = fmaf(sm_b[k], W2[k * 64 + tid], a);
        sm_a[tid] = fmaxf(a, 0.f);
    }
    __syncthreads();
    if (tid < 32) {
        float a = b3[tid];
        for (int k = 0; k < 64; ++k) a = fmaf(sm_a[k], W3[k * 32 + tid], a);
        sm_b[tid] = fmaxf(a, 0.f);
    }
    __syncthreads();
    if (tid < 2) {
        float a = b4[tid];
        for (int k = 0; k < 32; ++k) a = fmaf(sm_b[k], W4[k * 2 + tid], a);
        out[b * 2 + tid] = a;
    }
}

extern "C" void kernel_launch(void* const* d_in, const int* in_sizes, int n_in,
                              void* d_out, int out_size, void* d_ws, size_t ws_size,
                              hipStream_t stream) {
    const float* x    = (const float*)d_in[0];
    const float* Wi1  = (const float*)d_in[1];
    const float* bi1  = (const float*)d_in[2];
    const float* Whr1 = (const float*)d_in[3];
    const float* Whz1 = (const float*)d_in[4];
    const float* Whn1 = (const float*)d_in[5];
    const float* bhn1 = (const float*)d_in[6];
    const float* Wi2  = (const float*)d_in[7];
    const float* bi2  = (const float*)d_in[8];
    const float* Whr2 = (const float*)d_in[9];
    const float* Whz2 = (const float*)d_in[10];
    const float* Whn2 = (const float*)d_in[11];
    const float* bhn2 = (const float*)d_in[12];
    const float* Wp   = (const float*)d_in[13];
    const float* bp   = (const float*)d_in[14];
    const float* Wa   = (const float*)d_in[15];
    // d_in[16] = ba: softmax shift-invariant, unused
    const float* W1   = (const float*)d_in[17];
    const float* b1   = (const float*)d_in[18];
    const float* W2   = (const float*)d_in[19];
    const float* b2   = (const float*)d_in[20];
    const float* W3   = (const float*)d_in[21];
    const float* b3   = (const float*)d_in[22];
    const float* W4   = (const float*)d_in[23];
    const float* b4   = (const float*)d_in[24];

    solar_rnn<<<dim3(B_), dim3(512), 0, stream>>>(
        x, Wi1, bi1, Whr1, Whz1, Whn1, bhn1,
        Wi2, bi2, Whr2, Whz2, Whn2, bhn2,
        Wp, bp, Wa, W1, b1, W2, b2, W3, b3, W4, b4,
        (float*)d_out);
}